// Round 15
// baseline (197.033 us; speedup 1.0000x reference)
//
#include <hip/hip_runtime.h>
#include <hip/hip_fp16.h>
#include <math.h>

#define B_ 128
#define C_ 10
#define R_ 8192
#define I_ 8
#define O_ 16

typedef __attribute__((ext_vector_type(8))) _Float16 half8;
typedef __attribute__((ext_vector_type(16))) float f32x16;

#define XROW 512           // uints per x r-row: 128 b * 4
#define WROW 64            // uints per W row: 16 o * 4
#define WZERO 80           // zero-row index (shared by both A variants)
#define SBO (C_ * B_ * O_) // 20480
#define SLOTS 512          // part slots (one per block, 16 r-rows each)
#define RROW 12            // red row stride in uints (48 B: 16B-aligned, bank-spread)
#define LOG2E 1.44269504088896f

__device__ __forceinline__ unsigned pk2(float a, float b) {
    __half2 h = __floats2half2_rn(a, b);
    return *(unsigned*)&h;
}

// dot of u-half with (va,vb) as TWO independent 4-chains (ILP 4 with p0/p1):
// at 4 waves/SIMD the serial 8-chain left FMA latency uncovered (r12/r13
// effective ~5 cyc/inst; r14 confirmed: -2.5us). fp32 reassociation only.
#define DOT8(U, base, va, vb)                                                  \
    ((U[base + 0] * va.x + U[base + 2] * va.z + U[base + 4] * vb.x + U[base + 6] * vb.z) + \
     (U[base + 1] * va.y + U[base + 3] * va.w + U[base + 5] * vb.y + U[base + 7] * vb.w))

// ---------------------------------------------------------------------------
// fused_iter: one routing iteration. grid 512, block 512 (8 waves), TR=16.
// Structure: r9 in-block LDS reduction (part = 21 MB), r10 zero16 C-op,
// r13 phase-3 weighting on the matrix pipe (full-A MFMA with x*cij),
// r14 DOT8 reassociation.
// r15 changes (both chain-VALU cuts; ledger has TLP/ILP/permlane closed):
//  - exp2f instead of __expf: log2e is pre-folded into vsum by finish_fused
//    (linear in v, so the b_ij accumulation commutes; `out` path unscaled).
//    Deletes 80 muls/wave from the softmax dependency chain.
//  - red flush write = ONE ds_write_b128/lane (was 2x b64): row permuted to
//    pos0-3 = g0 pairs {o01,o23,o89,o10_11}, pos4-7 = g1 pairs; stride 12
//    uints (48 B) keeps 16B alignment and spreads all 32 banks over 8 lanes.
// Spill tripwire: WRITE_SIZE must stay 20480 KB exactly.
// ---------------------------------------------------------------------------
__global__ __launch_bounds__(512, 4) void fused_iter(const float* __restrict__ x,
                                                     const float* __restrict__ w,
                                                     const float* __restrict__ vsum,  // [C][B][16], pre-scaled by log2e
                                                     __half* __restrict__ part,
                                                     int mode) {
    __shared__ unsigned xls[2 * 8 * XROW];       // 32 KB; dead after hoist -> red buffer
    __shared__ unsigned wls[2 * 81 * WROW];      // 40.5 KB (two subtiles, each + zero row)

    const int tid  = threadIdx.x;
    const int wave = tid >> 6;
    const int sg   = wave >> 2;          // subtile 0/1
    const int stid = tid & 255;          // id within subgroup
    const int lane = tid & 63;
    const int n    = lane & 31;
    const int g    = lane >> 5;          // k-half / o-half selector
    const int rp_m = (lane & 31) >> 4;   // r' of this lane's A row (block-diag)
    const int o_m  = lane & 15;          // o of this lane's A row
    const int b    = (wave & 3) * 32 + n;
    const int r0   = blockIdx.x * 16 + sg * 8;

    unsigned* const xbase = xls + sg * (8 * XROW);
    unsigned* const wbase = wls + sg * (81 * WROW);
    unsigned* const red_u = xls;         // [cp(2)][s(2)][b(128)][RROW] uints (fp16 x2)

    // ---- stage x subtile fp16, XOR-swizzled (r4-verified) ----
#pragma unroll
    for (int k = 0; k < 8; ++k) {
        const int f = k * 256 + stid;            // 0..2047
        const int bb = f >> 4;
        const int rr = (f >> 1) & 7;
        const int q = f & 1;
        const float4 v = *(const float4*)(x + ((size_t)bb * R_ + r0 + rr) * 8 + q * 4);
        *(uint2*)(xbase + rr * XROW + ((bb * 4 + q * 2) ^ (rr << 2))) =
            make_uint2(pk2(v.x, v.y), pk2(v.z, v.w));
    }
    // ---- stage W subtile for ALL c fp16: [c*8+r][o][4 b32] ----
#pragma unroll
    for (int k = 0; k < 5; ++k) {
        const int id = k * 256 + stid;           // 0..1279 = (c, r, o)
        const int o = id & 15;
        const int r = (id >> 4) & 7;
        const int c = id >> 7;
        const float* wp = w + ((size_t)(c * R_ + r0 + r) * 8) * 16 + o;
        const float f0 = wp[0],  f1 = wp[16],  f2 = wp[32],  f3 = wp[48];
        const float f4 = wp[64], f5 = wp[80],  f6 = wp[96],  f7 = wp[112];
        *(uint4*)(wbase + (c * 8 + r) * WROW + o * 4) =
            make_uint4(pk2(f0, f1), pk2(f2, f3), pk2(f4, f5), pk2(f6, f7));
    }
    if (stid < WROW) wbase[WZERO * WROW + stid] = 0u;
    __syncthreads();

    const int act = (g == rp_m);         // block-diag A activity
    const int actf = (rp_m == 0);        // full-A activity (rows m = o < 16)

    // hoisted x fragments (c-invariant); read compensates the swizzle
    half8 xbr[4];
#pragma unroll
    for (int rp = 0; rp < 4; ++rp) {
        const int row = 2 * rp + g;
        xbr[rp] = *(const half8*)(xbase + row * XROW + ((b * 4) ^ (row << 2)));
    }
    __syncthreads();    // xls reads done -> red_u aliasing is now safe

    // hoisted zero accumulator: MFMA C operand (D != C), no per-use init
    f32x16 zero16;
#pragma unroll
    for (int j = 0; j < 16; ++j) zero16[j] = 0.f;

// red write (this sg's 8-row fp16 partial) + 2-c-batch flush.
// Lane writes ONE uint4 at pos g*4 (row layout: pos0-3 = g0's {o01,o23,o89,
// o10_11}, pos4-7 = g1's {o45,o67,o12_13,o14_15}).
// Flush (oh-half): uint2 at +2*oh gives o(8oh)..o(8oh+3), uint2 at +4+2*oh
// gives o(8oh+4)..o(8oh+7); sums sg0+sg1 in fp32, coalesced uint4 to part.
#define RED_WRITE_AND_FLUSH(A0,A1,A2,A3,A4,A5,A6,A7)                           \
    {                                                                          \
        const int cp = c & 1;                                                  \
        unsigned* rw = red_u + ((cp * 2 + sg) * 128 + b) * RROW;               \
        *(uint4*)(rw + g * 4) = make_uint4(pk2(A0, A1), pk2(A2, A3),           \
                                           pk2(A4, A5), pk2(A6, A7));          \
        if (cp == 1) {                                                         \
            __syncthreads();                                                   \
            const int cp2 = tid >> 8, t2 = tid & 255;                          \
            const int b2 = t2 >> 1, oh = t2 & 1;                               \
            const int cout = c - 1 + cp2;                                      \
            const unsigned* r0p = red_u + ((cp2 * 2 + 0) * 128 + b2) * RROW + oh * 2; \
            const unsigned* r1p = red_u + ((cp2 * 2 + 1) * 128 + b2) * RROW + oh * 2; \
            const uint2 xa = *(const uint2*)r0p;                               \
            const uint2 xb2 = *(const uint2*)(r0p + 4);                        \
            const uint2 ya = *(const uint2*)r1p;                               \
            const uint2 yb = *(const uint2*)(r1p + 4);                         \
            unsigned ua[4] = {xa.x, xa.y, xb2.x, xb2.y};                       \
            unsigned ub[4] = {ya.x, ya.y, yb.x, yb.y};                         \
            unsigned uo[4];                                                    \
            _Pragma("unroll")                                                  \
            for (int j = 0; j < 4; ++j) {                                      \
                const float2 fa = __half22float2(*(const __half2*)&ua[j]);     \
                const float2 fb = __half22float2(*(const __half2*)&ub[j]);     \
                uo[j] = pk2(fa.x + fb.x, fa.y + fb.y);                         \
            }                                                                  \
            *(uint4*)(part + ((size_t)blockIdx.x * C_ + cout) * (B_ * O_)      \
                      + b2 * O_ + oh * 8) = make_uint4(uo[0], uo[1], uo[2], uo[3]); \
            __syncthreads();                                                   \
        }                                                                      \
    }

    if (mode) {
        // ================= mode 1: softmax-weighted =================
        // ---- phase 2: denominators d[r] = sum_c exp2(p[c,r]) ----
        float dinv[4];
        {
            float dacc[4] = {0.f, 0.f, 0.f, 0.f};
#pragma unroll 1
            for (int c = 0; c < C_; ++c) {
                const float4* vp = (const float4*)(vsum + ((size_t)c * B_ + b) * O_ + 4 * g);
                const float4 va = vp[0];   // o = 4g..4g+3 (pre-scaled by log2e)
                const float4 vb = vp[2];   // o = 8+4g..
#pragma unroll
                for (int rp = 0; rp < 4; ++rp) {
                    const int woff = act ? ((c * 8 + 2 * rp + g) * WROW + o_m * 4)
                                         : (WZERO * WROW);
                    const half8 a = *(const half8*)(wbase + woff);
                    const f32x16 u = __builtin_amdgcn_mfma_f32_32x32x16_f16(a, xbr[rp], zero16, 0, 0, 0);
                    const float p0 = DOT8(u, 0, va, vb);
                    const float p1 = DOT8(u, 8, va, vb);
                    const float send = g ? p0 : p1;
                    const float recv = __shfl_xor(send, 32);
                    const float pg = (g ? p1 : p0) + recv;
                    dacc[rp] += exp2f(pg);
                }
            }
#pragma unroll
            for (int rp = 0; rp < 4; ++rp) dinv[rp] = 1.0f / dacc[rp];
        }

        // ---- phase 3: weighted accumulation via full-A MFMA ----
#pragma unroll 1
        for (int c = 0; c < C_; ++c) {
            const float4* vp = (const float4*)(vsum + ((size_t)c * B_ + b) * O_ + 4 * g);
            const float4 va = vp[0];
            const float4 vb = vp[2];
            f32x16 sacc;
#pragma unroll
            for (int rp = 0; rp < 4; ++rp) {
                const int wslot = (c * 8 + 2 * rp + g) * WROW + o_m * 4;
                const int woff_d = act ? wslot : (WZERO * WROW);
                const half8 ad = *(const half8*)(wbase + woff_d);
                const f32x16 u = __builtin_amdgcn_mfma_f32_32x32x16_f16(ad, xbr[rp], zero16, 0, 0, 0);
                const float p0 = DOT8(u, 0, va, vb);
                const float p1 = DOT8(u, 8, va, vb);
                const float send = g ? p0 : p1;
                const float recv = __shfl_xor(send, 32);
                const float pg = (g ? p1 : p0) + recv;
                const float w_own = exp2f(pg) * dinv[rp];    // cij for r = 2rp+g
                const _Float16 wh = (_Float16)w_own;
                half8 xc;
#pragma unroll
                for (int j = 0; j < 8; ++j) xc[j] = (_Float16)(xbr[rp][j] * wh);
                const int woff_f = actf ? wslot : (WZERO * WROW);
                const half8 af = *(const half8*)(wbase + woff_f);
                sacc = __builtin_amdgcn_mfma_f32_32x32x16_f16(af, xc,
                                                              rp == 0 ? zero16 : sacc, 0, 0, 0);
            }
            RED_WRITE_AND_FLUSH(sacc[0], sacc[1], sacc[2], sacc[3],
                                sacc[4], sacc[5], sacc[6], sacc[7]);
        }
    } else {
        // ================= mode 0: uniform weights 0.1 (full-A, no r-fold) =====
#pragma unroll 1
        for (int c = 0; c < C_; ++c) {
            f32x16 acc;
#pragma unroll
            for (int rp = 0; rp < 4; ++rp) {
                const int woff_f = actf ? ((c * 8 + 2 * rp + g) * WROW + o_m * 4)
                                        : (WZERO * WROW);
                const half8 af = *(const half8*)(wbase + woff_f);
                acc = __builtin_amdgcn_mfma_f32_32x32x16_f16(af, xbr[rp],
                                                             rp == 0 ? zero16 : acc, 0, 0, 0);
            }
            const float f0 = acc[0] * 0.1f, f1 = acc[1] * 0.1f;
            const float f2 = acc[2] * 0.1f, f3 = acc[3] * 0.1f;
            const float f4 = acc[4] * 0.1f, f5 = acc[5] * 0.1f;
            const float f6 = acc[6] * 0.1f, f7 = acc[7] * 0.1f;
            RED_WRITE_AND_FLUSH(f0, f1, f2, f3, f4, f5, f6, f7);
        }
    }
#undef RED_WRITE_AND_FLUSH
}

// ---------------------------------------------------------------------------
// finish_fused: vectorized uint4 loads (16 B/lane). grid 80, block 512.
// Block owns 32 uint4-cols; thread (jj = tid&31, sgp = tid>>5) sums 32 slots
// of col blockIdx*32+jj. LDS tree red[16][32][9] (pad 9 breaks 8-way bank
// conflict), then lanes 0..255 squash (16-lane groups = 16 o's) and write.
// r15: modes 0/1 write vsum PRE-SCALED by log2e (fused uses exp2f); the
// accumulation vsum += v*log2e is the scaled b_ij (linear, commutes).
// mode 2 writes `out` UNSCALED.
// ---------------------------------------------------------------------------
__global__ __launch_bounds__(512) void finish_fused(const __half* __restrict__ part,
                                                    float* __restrict__ vsum,   // [C][B][16] (x log2e)
                                                    float* __restrict__ out,    // [B][C][16]
                                                    int mode) {
    __shared__ float red[16][32][9];
    const int jj  = threadIdx.x & 31;
    const int sgp = threadIdx.x >> 5;          // slot-sixteenth 0..15
    const size_t col = (size_t)blockIdx.x * 32 + jj;   // uint4-column 0..2559

    const uint4* pu = (const uint4*)part + (size_t)(sgp * 32) * (SBO / 8) + col;
    float s[8];
#pragma unroll
    for (int e = 0; e < 8; ++e) s[e] = 0.f;
#pragma unroll 8
    for (int ss = 0; ss < 32; ++ss) {
        const uint4 v = pu[(size_t)ss * (SBO / 8)];
        const float2 f0 = __half22float2(*(const __half2*)&v.x);
        const float2 f1 = __half22float2(*(const __half2*)&v.y);
        const float2 f2 = __half22float2(*(const __half2*)&v.z);
        const float2 f3 = __half22float2(*(const __half2*)&v.w);
        s[0] += f0.x; s[1] += f0.y; s[2] += f1.x; s[3] += f1.y;
        s[4] += f2.x; s[5] += f2.y; s[6] += f3.x; s[7] += f3.y;
    }
#pragma unroll
    for (int e = 0; e < 8; ++e) red[sgp][jj][e] = s[e];
    __syncthreads();

    if (threadIdx.x < 256) {
        const int j2 = threadIdx.x >> 3;       // col within block 0..31
        const int e  = threadIdx.x & 7;
        float sum = red[0][j2][e];
#pragma unroll
        for (int k = 1; k < 16; ++k) sum += red[k][j2][e];

        float sq = sum * sum;
        sq += __shfl_xor(sq, 1);
        sq += __shfl_xor(sq, 2);
        sq += __shfl_xor(sq, 4);
        sq += __shfl_xor(sq, 8);
        const float scale = sq / ((1.0f + sq) * sqrtf(sq + 1e-8f));
        const float v = scale * sum;
        const size_t h = ((size_t)blockIdx.x * 32 + j2) * 8 + e;   // index in [C][B][16]

        if (mode == 0) {
            vsum[h] = v * LOG2E;
        } else if (mode == 1) {
            vsum[h] += v * LOG2E;
        } else {
            const int o = (int)(h & 15), b = (int)((h >> 4) & 127), c = (int)(h >> 11);
            out[((size_t)b * C_ + c) * O_ + o] = v;
        }
    }
}

extern "C" void kernel_launch(void* const* d_in, const int* in_sizes, int n_in,
                              void* d_out, int out_size, void* d_ws, size_t ws_size,
                              hipStream_t stream) {
    const float* x = (const float*)d_in[0];   // [B,R,8]
    const float* w = (const float*)d_in[1];   // [C,R,8,16]
    float* out = (float*)d_out;               // [B,C,16]

    __half* part = (__half*)d_ws;                          // 512*20480 fp16 = 21.0 MB
    float* vsum  = (float*)(part + (size_t)SLOTS * SBO);   // 20480 f ([C][B][16])

    const dim3 fgrid(R_ / 16);             // 512 blocks of 512 threads
    const dim3 ggrid(80);                  // finish_fused (32 uint4-cols each)

    for (int it = 0; it < 3; ++it) {
        const int mode = (it > 0);
        const int fmode = (it == 2) ? 2 : it;   // finish: 0=set, 1=add, 2=out
        fused_iter<<<fgrid, 512, 0, stream>>>(x, w, vsum, part, mode);
        finish_fused<<<ggrid, 512, 0, stream>>>(part, vsum, out, fmode);
    }
}

// Round 16
// 196.969 us; speedup vs baseline: 1.0003x; 1.0003x over previous
//
#include <hip/hip_runtime.h>
#include <hip/hip_fp16.h>
#include <math.h>

#define B_ 128
#define C_ 10
#define R_ 8192
#define I_ 8
#define O_ 16

typedef __attribute__((ext_vector_type(8))) _Float16 half8;
typedef __attribute__((ext_vector_type(16))) float f32x16;

#define XROW 512           // uints per x r-row: 128 b * 4
#define WROW 64            // uints per W row: 16 o * 4
#define WZERO 80           // zero-row index (shared by both A variants)
#define SBO (C_ * B_ * O_) // 20480
#define SLOTS 512          // part slots (one per block, 16 r-rows each)
#define LOG2E 1.44269504088896f

__device__ __forceinline__ unsigned pk2(float a, float b) {
    __half2 h = __floats2half2_rn(a, b);
    return *(unsigned*)&h;
}

// dot of u-half with (va,vb) as TWO independent 4-chains (ILP 4 with p0/p1):
// at 4 waves/SIMD the serial 8-chain left FMA latency uncovered (r14: -2.5us).
#define DOT8(U, base, va, vb)                                                  \
    ((U[base + 0] * va.x + U[base + 2] * va.z + U[base + 4] * vb.x + U[base + 6] * vb.z) + \
     (U[base + 1] * va.y + U[base + 3] * va.w + U[base + 5] * vb.y + U[base + 7] * vb.w))

// ---------------------------------------------------------------------------
// fused_iter: one routing iteration. grid 512, block 512 (8 waves), TR=16.
// Structure: r9 in-block LDS reduction (part = 21 MB), r10 zero16 C-op,
// r13 phase-3 weighting on the matrix pipe (full-A MFMA with x*cij),
// r14 DOT8 reassociation + conflict-free RROW=10 red layout.
// r16 = r14 + exp2f (vsum pre-scaled by log2e in finish_fused; -80 chain
// muls/wave). r15's RROW=12 b128 red-write REVERTED: bank = (b*12+4g)%32
// has period 8 in b -> 4-way conflict every flush (the r15 regression);
// r14's stride-10 b64 pair is conflict-free (b*10%32: 16 banks/16 lanes).
// Spill tripwire: WRITE_SIZE must stay 20480 KB exactly.
// ---------------------------------------------------------------------------
__global__ __launch_bounds__(512, 4) void fused_iter(const float* __restrict__ x,
                                                     const float* __restrict__ w,
                                                     const float* __restrict__ vsum,  // [C][B][16], pre-scaled by log2e
                                                     __half* __restrict__ part,
                                                     int mode) {
    __shared__ unsigned xls[2 * 8 * XROW];       // 32 KB; dead after hoist -> red buffer
    __shared__ unsigned wls[2 * 81 * WROW];      // 40.5 KB (two subtiles, each + zero row)

    const int tid  = threadIdx.x;
    const int wave = tid >> 6;
    const int sg   = wave >> 2;          // subtile 0/1
    const int stid = tid & 255;          // id within subgroup
    const int lane = tid & 63;
    const int n    = lane & 31;
    const int g    = lane >> 5;          // k-half / o-half selector
    const int rp_m = (lane & 31) >> 4;   // r' of this lane's A row (block-diag)
    const int o_m  = lane & 15;          // o of this lane's A row
    const int b    = (wave & 3) * 32 + n;
    const int r0   = blockIdx.x * 16 + sg * 8;

    unsigned* const xbase = xls + sg * (8 * XROW);
    unsigned* const wbase = wls + sg * (81 * WROW);
    unsigned* const red_u = xls;         // [cp(2)][s(2)][b(128)][10] uints (fp16 x2)

    // ---- stage x subtile fp16, XOR-swizzled (r4-verified) ----
#pragma unroll
    for (int k = 0; k < 8; ++k) {
        const int f = k * 256 + stid;            // 0..2047
        const int bb = f >> 4;
        const int rr = (f >> 1) & 7;
        const int q = f & 1;
        const float4 v = *(const float4*)(x + ((size_t)bb * R_ + r0 + rr) * 8 + q * 4);
        *(uint2*)(xbase + rr * XROW + ((bb * 4 + q * 2) ^ (rr << 2))) =
            make_uint2(pk2(v.x, v.y), pk2(v.z, v.w));
    }
    // ---- stage W subtile for ALL c fp16: [c*8+r][o][4 b32] ----
#pragma unroll
    for (int k = 0; k < 5; ++k) {
        const int id = k * 256 + stid;           // 0..1279 = (c, r, o)
        const int o = id & 15;
        const int r = (id >> 4) & 7;
        const int c = id >> 7;
        const float* wp = w + ((size_t)(c * R_ + r0 + r) * 8) * 16 + o;
        const float f0 = wp[0],  f1 = wp[16],  f2 = wp[32],  f3 = wp[48];
        const float f4 = wp[64], f5 = wp[80],  f6 = wp[96],  f7 = wp[112];
        *(uint4*)(wbase + (c * 8 + r) * WROW + o * 4) =
            make_uint4(pk2(f0, f1), pk2(f2, f3), pk2(f4, f5), pk2(f6, f7));
    }
    if (stid < WROW) wbase[WZERO * WROW + stid] = 0u;
    __syncthreads();

    const int act = (g == rp_m);         // block-diag A activity
    const int actf = (rp_m == 0);        // full-A activity (rows m = o < 16)

    // hoisted x fragments (c-invariant); read compensates the swizzle
    half8 xbr[4];
#pragma unroll
    for (int rp = 0; rp < 4; ++rp) {
        const int row = 2 * rp + g;
        xbr[rp] = *(const half8*)(xbase + row * XROW + ((b * 4) ^ (row << 2)));
    }
    __syncthreads();    // xls reads done -> red_u aliasing is now safe

    // hoisted zero accumulator: MFMA C operand (D != C), no per-use init
    f32x16 zero16;
#pragma unroll
    for (int j = 0; j < 16; ++j) zero16[j] = 0.f;

// red write (this sg's 8-row fp16 partial) + 2-c-batch flush (r14 layout:
// stride 10, two conflict-free uint2 writes per lane).
// flush sums sg0+sg1 in fp32, writes 16-row fp16 partial to part (coalesced).
#define RED_WRITE_AND_FLUSH(A0,A1,A2,A3,A4,A5,A6,A7)                           \
    {                                                                          \
        const int cp = c & 1;                                                  \
        unsigned* rw = red_u + ((cp * 2 + sg) * 128 + b) * 10;                 \
        *(uint2*)(rw + 2 * g)     = make_uint2(pk2(A0, A1), pk2(A2, A3));      \
        *(uint2*)(rw + 4 + 2 * g) = make_uint2(pk2(A4, A5), pk2(A6, A7));      \
        if (cp == 1) {                                                         \
            __syncthreads();                                                   \
            const int cp2 = tid >> 8, t2 = tid & 255;                          \
            const int b2 = t2 >> 1, oh = t2 & 1;                               \
            const int cout = c - 1 + cp2;                                      \
            const unsigned* r0p = red_u + ((cp2 * 2 + 0) * 128 + b2) * 10 + oh * 4; \
            const unsigned* r1p = red_u + ((cp2 * 2 + 1) * 128 + b2) * 10 + oh * 4; \
            const uint2 xa = *(const uint2*)r0p;                               \
            const uint2 xb2 = *(const uint2*)(r0p + 2);                        \
            const uint2 ya = *(const uint2*)r1p;                               \
            const uint2 yb = *(const uint2*)(r1p + 2);                         \
            unsigned ua[4] = {xa.x, xa.y, xb2.x, xb2.y};                       \
            unsigned ub[4] = {ya.x, ya.y, yb.x, yb.y};                         \
            unsigned uo[4];                                                    \
            _Pragma("unroll")                                                  \
            for (int j = 0; j < 4; ++j) {                                      \
                const float2 fa = __half22float2(*(const __half2*)&ua[j]);     \
                const float2 fb = __half22float2(*(const __half2*)&ub[j]);     \
                uo[j] = pk2(fa.x + fb.x, fa.y + fb.y);                         \
            }                                                                  \
            *(uint4*)(part + ((size_t)blockIdx.x * C_ + cout) * (B_ * O_)      \
                      + b2 * O_ + oh * 8) = make_uint4(uo[0], uo[1], uo[2], uo[3]); \
            __syncthreads();                                                   \
        }                                                                      \
    }

    if (mode) {
        // ================= mode 1: softmax-weighted =================
        // ---- phase 2: denominators d[r] = sum_c exp2(p[c,r]) ----
        float dinv[4];
        {
            float dacc[4] = {0.f, 0.f, 0.f, 0.f};
#pragma unroll 1
            for (int c = 0; c < C_; ++c) {
                const float4* vp = (const float4*)(vsum + ((size_t)c * B_ + b) * O_ + 4 * g);
                const float4 va = vp[0];   // o = 4g..4g+3 (pre-scaled by log2e)
                const float4 vb = vp[2];   // o = 8+4g..
#pragma unroll
                for (int rp = 0; rp < 4; ++rp) {
                    const int woff = act ? ((c * 8 + 2 * rp + g) * WROW + o_m * 4)
                                         : (WZERO * WROW);
                    const half8 a = *(const half8*)(wbase + woff);
                    const f32x16 u = __builtin_amdgcn_mfma_f32_32x32x16_f16(a, xbr[rp], zero16, 0, 0, 0);
                    const float p0 = DOT8(u, 0, va, vb);
                    const float p1 = DOT8(u, 8, va, vb);
                    const float send = g ? p0 : p1;
                    const float recv = __shfl_xor(send, 32);
                    const float pg = (g ? p1 : p0) + recv;
                    dacc[rp] += exp2f(pg);
                }
            }
#pragma unroll
            for (int rp = 0; rp < 4; ++rp) dinv[rp] = 1.0f / dacc[rp];
        }

        // ---- phase 3: weighted accumulation via full-A MFMA ----
#pragma unroll 1
        for (int c = 0; c < C_; ++c) {
            const float4* vp = (const float4*)(vsum + ((size_t)c * B_ + b) * O_ + 4 * g);
            const float4 va = vp[0];
            const float4 vb = vp[2];
            f32x16 sacc;
#pragma unroll
            for (int rp = 0; rp < 4; ++rp) {
                const int wslot = (c * 8 + 2 * rp + g) * WROW + o_m * 4;
                const int woff_d = act ? wslot : (WZERO * WROW);
                const half8 ad = *(const half8*)(wbase + woff_d);
                const f32x16 u = __builtin_amdgcn_mfma_f32_32x32x16_f16(ad, xbr[rp], zero16, 0, 0, 0);
                const float p0 = DOT8(u, 0, va, vb);
                const float p1 = DOT8(u, 8, va, vb);
                const float send = g ? p0 : p1;
                const float recv = __shfl_xor(send, 32);
                const float pg = (g ? p1 : p0) + recv;
                const float w_own = exp2f(pg) * dinv[rp];    // cij for r = 2rp+g
                const _Float16 wh = (_Float16)w_own;
                half8 xc;
#pragma unroll
                for (int j = 0; j < 8; ++j) xc[j] = (_Float16)(xbr[rp][j] * wh);
                const int woff_f = actf ? wslot : (WZERO * WROW);
                const half8 af = *(const half8*)(wbase + woff_f);
                sacc = __builtin_amdgcn_mfma_f32_32x32x16_f16(af, xc,
                                                              rp == 0 ? zero16 : sacc, 0, 0, 0);
            }
            RED_WRITE_AND_FLUSH(sacc[0], sacc[1], sacc[2], sacc[3],
                                sacc[4], sacc[5], sacc[6], sacc[7]);
        }
    } else {
        // ================= mode 0: uniform weights 0.1 (full-A, no r-fold) =====
#pragma unroll 1
        for (int c = 0; c < C_; ++c) {
            f32x16 acc;
#pragma unroll
            for (int rp = 0; rp < 4; ++rp) {
                const int woff_f = actf ? ((c * 8 + 2 * rp + g) * WROW + o_m * 4)
                                        : (WZERO * WROW);
                const half8 af = *(const half8*)(wbase + woff_f);
                acc = __builtin_amdgcn_mfma_f32_32x32x16_f16(af, xbr[rp],
                                                             rp == 0 ? zero16 : acc, 0, 0, 0);
            }
            const float f0 = acc[0] * 0.1f, f1 = acc[1] * 0.1f;
            const float f2 = acc[2] * 0.1f, f3 = acc[3] * 0.1f;
            const float f4 = acc[4] * 0.1f, f5 = acc[5] * 0.1f;
            const float f6 = acc[6] * 0.1f, f7 = acc[7] * 0.1f;
            RED_WRITE_AND_FLUSH(f0, f1, f2, f3, f4, f5, f6, f7);
        }
    }
#undef RED_WRITE_AND_FLUSH
}

// ---------------------------------------------------------------------------
// finish_fused: vectorized uint4 loads (16 B/lane). grid 80, block 512.
// Block owns 32 uint4-cols; thread (jj = tid&31, sgp = tid>>5) sums 32 slots
// of col blockIdx*32+jj. LDS tree red[16][32][9] (pad 9 breaks 8-way bank
// conflict), then lanes 0..255 squash (16-lane groups = 16 o's) and write.
// Modes 0/1 write vsum PRE-SCALED by log2e (fused uses exp2f); accumulation
// vsum += v*log2e is the scaled b_ij (linear, commutes). mode 2: out UNSCALED.
// ---------------------------------------------------------------------------
__global__ __launch_bounds__(512) void finish_fused(const __half* __restrict__ part,
                                                    float* __restrict__ vsum,   // [C][B][16] (x log2e)
                                                    float* __restrict__ out,    // [B][C][16]
                                                    int mode) {
    __shared__ float red[16][32][9];
    const int jj  = threadIdx.x & 31;
    const int sgp = threadIdx.x >> 5;          // slot-sixteenth 0..15
    const size_t col = (size_t)blockIdx.x * 32 + jj;   // uint4-column 0..2559

    const uint4* pu = (const uint4*)part + (size_t)(sgp * 32) * (SBO / 8) + col;
    float s[8];
#pragma unroll
    for (int e = 0; e < 8; ++e) s[e] = 0.f;
#pragma unroll 8
    for (int ss = 0; ss < 32; ++ss) {
        const uint4 v = pu[(size_t)ss * (SBO / 8)];
        const float2 f0 = __half22float2(*(const __half2*)&v.x);
        const float2 f1 = __half22float2(*(const __half2*)&v.y);
        const float2 f2 = __half22float2(*(const __half2*)&v.z);
        const float2 f3 = __half22float2(*(const __half2*)&v.w);
        s[0] += f0.x; s[1] += f0.y; s[2] += f1.x; s[3] += f1.y;
        s[4] += f2.x; s[5] += f2.y; s[6] += f3.x; s[7] += f3.y;
    }
#pragma unroll
    for (int e = 0; e < 8; ++e) red[sgp][jj][e] = s[e];
    __syncthreads();

    if (threadIdx.x < 256) {
        const int j2 = threadIdx.x >> 3;       // col within block 0..31
        const int e  = threadIdx.x & 7;
        float sum = red[0][j2][e];
#pragma unroll
        for (int k = 1; k < 16; ++k) sum += red[k][j2][e];

        float sq = sum * sum;
        sq += __shfl_xor(sq, 1);
        sq += __shfl_xor(sq, 2);
        sq += __shfl_xor(sq, 4);
        sq += __shfl_xor(sq, 8);
        const float scale = sq / ((1.0f + sq) * sqrtf(sq + 1e-8f));
        const float v = scale * sum;
        const size_t h = ((size_t)blockIdx.x * 32 + j2) * 8 + e;   // index in [C][B][16]

        if (mode == 0) {
            vsum[h] = v * LOG2E;
        } else if (mode == 1) {
            vsum[h] += v * LOG2E;
        } else {
            const int o = (int)(h & 15), b = (int)((h >> 4) & 127), c = (int)(h >> 11);
            out[((size_t)b * C_ + c) * O_ + o] = v;
        }
    }
}

extern "C" void kernel_launch(void* const* d_in, const int* in_sizes, int n_in,
                              void* d_out, int out_size, void* d_ws, size_t ws_size,
                              hipStream_t stream) {
    const float* x = (const float*)d_in[0];   // [B,R,8]
    const float* w = (const float*)d_in[1];   // [C,R,8,16]
    float* out = (float*)d_out;               // [B,C,16]

    __half* part = (__half*)d_ws;                          // 512*20480 fp16 = 21.0 MB
    float* vsum  = (float*)(part + (size_t)SLOTS * SBO);   // 20480 f ([C][B][16])

    const dim3 fgrid(R_ / 16);             // 512 blocks of 512 threads
    const dim3 ggrid(80);                  // finish_fused (32 uint4-cols each)

    for (int it = 0; it < 3; ++it) {
        const int mode = (it > 0);
        const int fmode = (it == 2) ? 2 : it;   // finish: 0=set, 1=add, 2=out
        fused_iter<<<fgrid, 512, 0, stream>>>(x, w, vsum, part, mode);
        finish_fused<<<ggrid, 512, 0, stream>>>(part, vsum, out, fmode);
    }
}

// Round 17
// 192.364 us; speedup vs baseline: 1.0243x; 1.0239x over previous
//
#include <hip/hip_runtime.h>
#include <hip/hip_fp16.h>
#include <math.h>

#define B_ 128
#define C_ 10
#define R_ 8192
#define I_ 8
#define O_ 16

typedef __attribute__((ext_vector_type(8))) _Float16 half8;
typedef __attribute__((ext_vector_type(16))) float f32x16;

#define XROW 512           // uints per x r-row: 128 b * 4
#define WROW 64            // uints per W row: 16 o * 4
#define WZERO 80           // zero-row index (shared by both A variants)
#define SBO (C_ * B_ * O_) // 20480
#define SLOTS 512          // part slots (one per block, 16 r-rows each)
#define LOG2E 1.44269504088896f

__device__ __forceinline__ unsigned pk2(float a, float b) {
    __half2 h = __floats2half2_rn(a, b);
    return *(unsigned*)&h;
}

// native 2^x (one v_exp_f32). r15/r16 LESSON: exp2f() is the PRECISE OCML
// libcall (range/denormal handling, several extra ops) -- it cost +2us over
// r14's __expf. __builtin_amdgcn_exp2f is the raw instruction; combined with
// the log2e-prescaled vsum this makes the chain dot->shfl->add->v_exp with
// no mul and no libcall (strictly fewer ops than r14).
#if __has_builtin(__builtin_amdgcn_exp2f)
#define EXP2F(x) __builtin_amdgcn_exp2f(x)
#else
#define EXP2F(x) exp2f(x)
#endif

// dot of u-half with (va,vb) as TWO independent 4-chains (ILP 4 with p0/p1):
// at 4 waves/SIMD the serial 8-chain left FMA latency uncovered (r14: -2.5us).
#define DOT8(U, base, va, vb)                                                  \
    ((U[base + 0] * va.x + U[base + 2] * va.z + U[base + 4] * vb.x + U[base + 6] * vb.z) + \
     (U[base + 1] * va.y + U[base + 3] * va.w + U[base + 5] * vb.y + U[base + 7] * vb.w))

// ---------------------------------------------------------------------------
// fused_iter: one routing iteration. grid 512, block 512 (8 waves), TR=16.
// Structure: r9 in-block LDS reduction (part = 21 MB), r10 zero16 C-op,
// r13 phase-3 weighting on the matrix pipe (full-A MFMA with x*cij),
// r14 DOT8 reassociation + conflict-free RROW=10 red layout.
// r17 = r14 + native-exp2 (vsum pre-scaled by log2e in finish_fused).
// Spill tripwire: WRITE_SIZE must stay 20480 KB exactly.
// ---------------------------------------------------------------------------
__global__ __launch_bounds__(512, 4) void fused_iter(const float* __restrict__ x,
                                                     const float* __restrict__ w,
                                                     const float* __restrict__ vsum,  // [C][B][16], pre-scaled by log2e
                                                     __half* __restrict__ part,
                                                     int mode) {
    __shared__ unsigned xls[2 * 8 * XROW];       // 32 KB; dead after hoist -> red buffer
    __shared__ unsigned wls[2 * 81 * WROW];      // 40.5 KB (two subtiles, each + zero row)

    const int tid  = threadIdx.x;
    const int wave = tid >> 6;
    const int sg   = wave >> 2;          // subtile 0/1
    const int stid = tid & 255;          // id within subgroup
    const int lane = tid & 63;
    const int n    = lane & 31;
    const int g    = lane >> 5;          // k-half / o-half selector
    const int rp_m = (lane & 31) >> 4;   // r' of this lane's A row (block-diag)
    const int o_m  = lane & 15;          // o of this lane's A row
    const int b    = (wave & 3) * 32 + n;
    const int r0   = blockIdx.x * 16 + sg * 8;

    unsigned* const xbase = xls + sg * (8 * XROW);
    unsigned* const wbase = wls + sg * (81 * WROW);
    unsigned* const red_u = xls;         // [cp(2)][s(2)][b(128)][10] uints (fp16 x2)

    // ---- stage x subtile fp16, XOR-swizzled (r4-verified) ----
#pragma unroll
    for (int k = 0; k < 8; ++k) {
        const int f = k * 256 + stid;            // 0..2047
        const int bb = f >> 4;
        const int rr = (f >> 1) & 7;
        const int q = f & 1;
        const float4 v = *(const float4*)(x + ((size_t)bb * R_ + r0 + rr) * 8 + q * 4);
        *(uint2*)(xbase + rr * XROW + ((bb * 4 + q * 2) ^ (rr << 2))) =
            make_uint2(pk2(v.x, v.y), pk2(v.z, v.w));
    }
    // ---- stage W subtile for ALL c fp16: [c*8+r][o][4 b32] ----
#pragma unroll
    for (int k = 0; k < 5; ++k) {
        const int id = k * 256 + stid;           // 0..1279 = (c, r, o)
        const int o = id & 15;
        const int r = (id >> 4) & 7;
        const int c = id >> 7;
        const float* wp = w + ((size_t)(c * R_ + r0 + r) * 8) * 16 + o;
        const float f0 = wp[0],  f1 = wp[16],  f2 = wp[32],  f3 = wp[48];
        const float f4 = wp[64], f5 = wp[80],  f6 = wp[96],  f7 = wp[112];
        *(uint4*)(wbase + (c * 8 + r) * WROW + o * 4) =
            make_uint4(pk2(f0, f1), pk2(f2, f3), pk2(f4, f5), pk2(f6, f7));
    }
    if (stid < WROW) wbase[WZERO * WROW + stid] = 0u;
    __syncthreads();

    const int act = (g == rp_m);         // block-diag A activity
    const int actf = (rp_m == 0);        // full-A activity (rows m = o < 16)

    // hoisted x fragments (c-invariant); read compensates the swizzle
    half8 xbr[4];
#pragma unroll
    for (int rp = 0; rp < 4; ++rp) {
        const int row = 2 * rp + g;
        xbr[rp] = *(const half8*)(xbase + row * XROW + ((b * 4) ^ (row << 2)));
    }
    __syncthreads();    // xls reads done -> red_u aliasing is now safe

    // hoisted zero accumulator: MFMA C operand (D != C), no per-use init
    f32x16 zero16;
#pragma unroll
    for (int j = 0; j < 16; ++j) zero16[j] = 0.f;

// red write (this sg's 8-row fp16 partial) + 2-c-batch flush (r14 layout:
// stride 10, two conflict-free uint2 writes per lane).
// flush sums sg0+sg1 in fp32, writes 16-row fp16 partial to part (coalesced).
#define RED_WRITE_AND_FLUSH(A0,A1,A2,A3,A4,A5,A6,A7)                           \
    {                                                                          \
        const int cp = c & 1;                                                  \
        unsigned* rw = red_u + ((cp * 2 + sg) * 128 + b) * 10;                 \
        *(uint2*)(rw + 2 * g)     = make_uint2(pk2(A0, A1), pk2(A2, A3));      \
        *(uint2*)(rw + 4 + 2 * g) = make_uint2(pk2(A4, A5), pk2(A6, A7));      \
        if (cp == 1) {                                                         \
            __syncthreads();                                                   \
            const int cp2 = tid >> 8, t2 = tid & 255;                          \
            const int b2 = t2 >> 1, oh = t2 & 1;                               \
            const int cout = c - 1 + cp2;                                      \
            const unsigned* r0p = red_u + ((cp2 * 2 + 0) * 128 + b2) * 10 + oh * 4; \
            const unsigned* r1p = red_u + ((cp2 * 2 + 1) * 128 + b2) * 10 + oh * 4; \
            const uint2 xa = *(const uint2*)r0p;                               \
            const uint2 xb2 = *(const uint2*)(r0p + 2);                        \
            const uint2 ya = *(const uint2*)r1p;                               \
            const uint2 yb = *(const uint2*)(r1p + 2);                         \
            unsigned ua[4] = {xa.x, xa.y, xb2.x, xb2.y};                       \
            unsigned ub[4] = {ya.x, ya.y, yb.x, yb.y};                         \
            unsigned uo[4];                                                    \
            _Pragma("unroll")                                                  \
            for (int j = 0; j < 4; ++j) {                                      \
                const float2 fa = __half22float2(*(const __half2*)&ua[j]);     \
                const float2 fb = __half22float2(*(const __half2*)&ub[j]);     \
                uo[j] = pk2(fa.x + fb.x, fa.y + fb.y);                         \
            }                                                                  \
            *(uint4*)(part + ((size_t)blockIdx.x * C_ + cout) * (B_ * O_)      \
                      + b2 * O_ + oh * 8) = make_uint4(uo[0], uo[1], uo[2], uo[3]); \
            __syncthreads();                                                   \
        }                                                                      \
    }

    if (mode) {
        // ================= mode 1: softmax-weighted =================
        // ---- phase 2: denominators d[r] = sum_c exp2(p[c,r]) ----
        float dinv[4];
        {
            float dacc[4] = {0.f, 0.f, 0.f, 0.f};
#pragma unroll 1
            for (int c = 0; c < C_; ++c) {
                const float4* vp = (const float4*)(vsum + ((size_t)c * B_ + b) * O_ + 4 * g);
                const float4 va = vp[0];   // o = 4g..4g+3 (pre-scaled by log2e)
                const float4 vb = vp[2];   // o = 8+4g..
#pragma unroll
                for (int rp = 0; rp < 4; ++rp) {
                    const int woff = act ? ((c * 8 + 2 * rp + g) * WROW + o_m * 4)
                                         : (WZERO * WROW);
                    const half8 a = *(const half8*)(wbase + woff);
                    const f32x16 u = __builtin_amdgcn_mfma_f32_32x32x16_f16(a, xbr[rp], zero16, 0, 0, 0);
                    const float p0 = DOT8(u, 0, va, vb);
                    const float p1 = DOT8(u, 8, va, vb);
                    const float send = g ? p0 : p1;
                    const float recv = __shfl_xor(send, 32);
                    const float pg = (g ? p1 : p0) + recv;
                    dacc[rp] += EXP2F(pg);
                }
            }
#pragma unroll
            for (int rp = 0; rp < 4; ++rp) dinv[rp] = 1.0f / dacc[rp];
        }

        // ---- phase 3: weighted accumulation via full-A MFMA ----
#pragma unroll 1
        for (int c = 0; c < C_; ++c) {
            const float4* vp = (const float4*)(vsum + ((size_t)c * B_ + b) * O_ + 4 * g);
            const float4 va = vp[0];
            const float4 vb = vp[2];
            f32x16 sacc;
#pragma unroll
            for (int rp = 0; rp < 4; ++rp) {
                const int wslot = (c * 8 + 2 * rp + g) * WROW + o_m * 4;
                const int woff_d = act ? wslot : (WZERO * WROW);
                const half8 ad = *(const half8*)(wbase + woff_d);
                const f32x16 u = __builtin_amdgcn_mfma_f32_32x32x16_f16(ad, xbr[rp], zero16, 0, 0, 0);
                const float p0 = DOT8(u, 0, va, vb);
                const float p1 = DOT8(u, 8, va, vb);
                const float send = g ? p0 : p1;
                const float recv = __shfl_xor(send, 32);
                const float pg = (g ? p1 : p0) + recv;
                const float w_own = EXP2F(pg) * dinv[rp];    // cij for r = 2rp+g
                const _Float16 wh = (_Float16)w_own;
                half8 xc;
#pragma unroll
                for (int j = 0; j < 8; ++j) xc[j] = (_Float16)(xbr[rp][j] * wh);
                const int woff_f = actf ? wslot : (WZERO * WROW);
                const half8 af = *(const half8*)(wbase + woff_f);
                sacc = __builtin_amdgcn_mfma_f32_32x32x16_f16(af, xc,
                                                              rp == 0 ? zero16 : sacc, 0, 0, 0);
            }
            RED_WRITE_AND_FLUSH(sacc[0], sacc[1], sacc[2], sacc[3],
                                sacc[4], sacc[5], sacc[6], sacc[7]);
        }
    } else {
        // ================= mode 0: uniform weights 0.1 (full-A, no r-fold) =====
#pragma unroll 1
        for (int c = 0; c < C_; ++c) {
            f32x16 acc;
#pragma unroll
            for (int rp = 0; rp < 4; ++rp) {
                const int woff_f = actf ? ((c * 8 + 2 * rp + g) * WROW + o_m * 4)
                                        : (WZERO * WROW);
                const half8 af = *(const half8*)(wbase + woff_f);
                acc = __builtin_amdgcn_mfma_f32_32x32x16_f16(af, xbr[rp],
                                                             rp == 0 ? zero16 : acc, 0, 0, 0);
            }
            const float f0 = acc[0] * 0.1f, f1 = acc[1] * 0.1f;
            const float f2 = acc[2] * 0.1f, f3 = acc[3] * 0.1f;
            const float f4 = acc[4] * 0.1f, f5 = acc[5] * 0.1f;
            const float f6 = acc[6] * 0.1f, f7 = acc[7] * 0.1f;
            RED_WRITE_AND_FLUSH(f0, f1, f2, f3, f4, f5, f6, f7);
        }
    }
#undef RED_WRITE_AND_FLUSH
}

// ---------------------------------------------------------------------------
// finish_fused: vectorized uint4 loads (16 B/lane). grid 80, block 512.
// Block owns 32 uint4-cols; thread (jj = tid&31, sgp = tid>>5) sums 32 slots
// of col blockIdx*32+jj. LDS tree red[16][32][9] (pad 9 breaks 8-way bank
// conflict), then lanes 0..255 squash (16-lane groups = 16 o's) and write.
// Modes 0/1 write vsum PRE-SCALED by log2e (fused uses native exp2);
// accumulation vsum += v*log2e is the scaled b_ij (linear, commutes).
// mode 2: out UNSCALED.
// ---------------------------------------------------------------------------
__global__ __launch_bounds__(512) void finish_fused(const __half* __restrict__ part,
                                                    float* __restrict__ vsum,   // [C][B][16] (x log2e)
                                                    float* __restrict__ out,    // [B][C][16]
                                                    int mode) {
    __shared__ float red[16][32][9];
    const int jj  = threadIdx.x & 31;
    const int sgp = threadIdx.x >> 5;          // slot-sixteenth 0..15
    const size_t col = (size_t)blockIdx.x * 32 + jj;   // uint4-column 0..2559

    const uint4* pu = (const uint4*)part + (size_t)(sgp * 32) * (SBO / 8) + col;
    float s[8];
#pragma unroll
    for (int e = 0; e < 8; ++e) s[e] = 0.f;
#pragma unroll 8
    for (int ss = 0; ss < 32; ++ss) {
        const uint4 v = pu[(size_t)ss * (SBO / 8)];
        const float2 f0 = __half22float2(*(const __half2*)&v.x);
        const float2 f1 = __half22float2(*(const __half2*)&v.y);
        const float2 f2 = __half22float2(*(const __half2*)&v.z);
        const float2 f3 = __half22float2(*(const __half2*)&v.w);
        s[0] += f0.x; s[1] += f0.y; s[2] += f1.x; s[3] += f1.y;
        s[4] += f2.x; s[5] += f2.y; s[6] += f3.x; s[7] += f3.y;
    }
#pragma unroll
    for (int e = 0; e < 8; ++e) red[sgp][jj][e] = s[e];
    __syncthreads();

    if (threadIdx.x < 256) {
        const int j2 = threadIdx.x >> 3;       // col within block 0..31
        const int e  = threadIdx.x & 7;
        float sum = red[0][j2][e];
#pragma unroll
        for (int k = 1; k < 16; ++k) sum += red[k][j2][e];

        float sq = sum * sum;
        sq += __shfl_xor(sq, 1);
        sq += __shfl_xor(sq, 2);
        sq += __shfl_xor(sq, 4);
        sq += __shfl_xor(sq, 8);
        const float scale = sq / ((1.0f + sq) * sqrtf(sq + 1e-8f));
        const float v = scale * sum;
        const size_t h = ((size_t)blockIdx.x * 32 + j2) * 8 + e;   // index in [C][B][16]

        if (mode == 0) {
            vsum[h] = v * LOG2E;
        } else if (mode == 1) {
            vsum[h] += v * LOG2E;
        } else {
            const int o = (int)(h & 15), b = (int)((h >> 4) & 127), c = (int)(h >> 11);
            out[((size_t)b * C_ + c) * O_ + o] = v;
        }
    }
}

extern "C" void kernel_launch(void* const* d_in, const int* in_sizes, int n_in,
                              void* d_out, int out_size, void* d_ws, size_t ws_size,
                              hipStream_t stream) {
    const float* x = (const float*)d_in[0];   // [B,R,8]
    const float* w = (const float*)d_in[1];   // [C,R,8,16]
    float* out = (float*)d_out;               // [B,C,16]

    __half* part = (__half*)d_ws;                          // 512*20480 fp16 = 21.0 MB
    float* vsum  = (float*)(part + (size_t)SLOTS * SBO);   // 20480 f ([C][B][16])

    const dim3 fgrid(R_ / 16);             // 512 blocks of 512 threads
    const dim3 ggrid(80);                  // finish_fused (32 uint4-cols each)

    for (int it = 0; it < 3; ++it) {
        const int mode = (it > 0);
        const int fmode = (it == 2) ? 2 : it;   // finish: 0=set, 1=add, 2=out
        fused_iter<<<fgrid, 512, 0, stream>>>(x, w, vsum, part, mode);
        finish_fused<<<ggrid, 512, 0, stream>>>(part, vsum, out, fmode);
    }
}

// Round 18
// 190.036 us; speedup vs baseline: 1.0368x; 1.0122x over previous
//
#include <hip/hip_runtime.h>
#include <hip/hip_fp16.h>
#include <math.h>

#define B_ 128
#define C_ 10
#define R_ 8192
#define I_ 8
#define O_ 16

typedef __attribute__((ext_vector_type(8))) _Float16 half8;
typedef __attribute__((ext_vector_type(16))) float f32x16;

#define XROW 512           // uints per x r-row: 128 b * 4
#define WROW 64            // uints per W row: 16 o * 4
#define WZERO 80           // zero-row index (shared by both A variants)
#define SBO (C_ * B_ * O_) // 20480
#define SLOTS 512          // part slots (one per block, 16 r-rows each)
#define LOG2E 1.44269504088896f

__device__ __forceinline__ unsigned pk2(float a, float b) {
    __half2 h = __floats2half2_rn(a, b);
    return *(unsigned*)&h;
}

// native 2^x (one v_exp_f32). r15/r16 lesson: exp2f() is the PRECISE OCML
// libcall (+2us); __builtin_amdgcn_exp2f is the raw instruction (r17: -1.5us
// vs __expf, with log2e pre-folded into vsum).
#if __has_builtin(__builtin_amdgcn_exp2f)
#define EXP2F(x) __builtin_amdgcn_exp2f(x)
#else
#define EXP2F(x) exp2f(x)
#endif

// dot of u-half with (va,vb) as TWO independent 4-chains (ILP 4 with p0/p1):
// at 4 waves/SIMD the serial 8-chain left FMA latency uncovered (r14: -2.5us).
#define DOT8(U, base, va, vb)                                                  \
    ((U[base + 0] * va.x + U[base + 2] * va.z + U[base + 4] * vb.x + U[base + 6] * vb.z) + \
     (U[base + 1] * va.y + U[base + 3] * va.w + U[base + 5] * vb.y + U[base + 7] * vb.w))

// ---------------------------------------------------------------------------
// fused_iter: one routing iteration. grid 512, block 512 (8 waves), TR=16.
// Structure: r9 in-block LDS reduction (part = 21 MB), r10 zero16 C-op,
// r13 phase-3 weighting on the matrix pipe (full-A MFMA with x*cij),
// r14 DOT8 reassociation + conflict-free RROW=10 red layout, r17 native exp2.
// r18 change: depth-1 software pipeline on the vsum (va,vb) loads in both
// phases -- the two global_load_dwordx4 at the top of each c-iteration were
// the last serial chain element (L2-hit ~200cy, only partly covered by the
// rp-MFMAs). Prefetch c+1's pair during c (clamped index at tail, +8 VGPRs).
// Spill tripwire: WRITE_SIZE must stay 20480 KB exactly.
// ---------------------------------------------------------------------------
__global__ __launch_bounds__(512, 4) void fused_iter(const float* __restrict__ x,
                                                     const float* __restrict__ w,
                                                     const float* __restrict__ vsum,  // [C][B][16], pre-scaled by log2e
                                                     __half* __restrict__ part,
                                                     int mode) {
    __shared__ unsigned xls[2 * 8 * XROW];       // 32 KB; dead after hoist -> red buffer
    __shared__ unsigned wls[2 * 81 * WROW];      // 40.5 KB (two subtiles, each + zero row)

    const int tid  = threadIdx.x;
    const int wave = tid >> 6;
    const int sg   = wave >> 2;          // subtile 0/1
    const int stid = tid & 255;          // id within subgroup
    const int lane = tid & 63;
    const int n    = lane & 31;
    const int g    = lane >> 5;          // k-half / o-half selector
    const int rp_m = (lane & 31) >> 4;   // r' of this lane's A row (block-diag)
    const int o_m  = lane & 15;          // o of this lane's A row
    const int b    = (wave & 3) * 32 + n;
    const int r0   = blockIdx.x * 16 + sg * 8;

    unsigned* const xbase = xls + sg * (8 * XROW);
    unsigned* const wbase = wls + sg * (81 * WROW);
    unsigned* const red_u = xls;         // [cp(2)][s(2)][b(128)][10] uints (fp16 x2)

    // ---- stage x subtile fp16, XOR-swizzled (r4-verified) ----
#pragma unroll
    for (int k = 0; k < 8; ++k) {
        const int f = k * 256 + stid;            // 0..2047
        const int bb = f >> 4;
        const int rr = (f >> 1) & 7;
        const int q = f & 1;
        const float4 v = *(const float4*)(x + ((size_t)bb * R_ + r0 + rr) * 8 + q * 4);
        *(uint2*)(xbase + rr * XROW + ((bb * 4 + q * 2) ^ (rr << 2))) =
            make_uint2(pk2(v.x, v.y), pk2(v.z, v.w));
    }
    // ---- stage W subtile for ALL c fp16: [c*8+r][o][4 b32] ----
#pragma unroll
    for (int k = 0; k < 5; ++k) {
        const int id = k * 256 + stid;           // 0..1279 = (c, r, o)
        const int o = id & 15;
        const int r = (id >> 4) & 7;
        const int c = id >> 7;
        const float* wp = w + ((size_t)(c * R_ + r0 + r) * 8) * 16 + o;
        const float f0 = wp[0],  f1 = wp[16],  f2 = wp[32],  f3 = wp[48];
        const float f4 = wp[64], f5 = wp[80],  f6 = wp[96],  f7 = wp[112];
        *(uint4*)(wbase + (c * 8 + r) * WROW + o * 4) =
            make_uint4(pk2(f0, f1), pk2(f2, f3), pk2(f4, f5), pk2(f6, f7));
    }
    if (stid < WROW) wbase[WZERO * WROW + stid] = 0u;
    __syncthreads();

    const int act = (g == rp_m);         // block-diag A activity
    const int actf = (rp_m == 0);        // full-A activity (rows m = o < 16)

    // hoisted x fragments (c-invariant); read compensates the swizzle
    half8 xbr[4];
#pragma unroll
    for (int rp = 0; rp < 4; ++rp) {
        const int row = 2 * rp + g;
        xbr[rp] = *(const half8*)(xbase + row * XROW + ((b * 4) ^ (row << 2)));
    }
    __syncthreads();    // xls reads done -> red_u aliasing is now safe

    // hoisted zero accumulator: MFMA C operand (D != C), no per-use init
    f32x16 zero16;
#pragma unroll
    for (int j = 0; j < 16; ++j) zero16[j] = 0.f;

    // base for this lane's vsum pair (c-stride = B_*O_ floats)
    const float* const vbase = vsum + ((size_t)b) * O_ + 4 * g;

// red write (this sg's 8-row fp16 partial) + 2-c-batch flush (r14 layout:
// stride 10, two conflict-free uint2 writes per lane).
// flush sums sg0+sg1 in fp32, writes 16-row fp16 partial to part (coalesced).
#define RED_WRITE_AND_FLUSH(A0,A1,A2,A3,A4,A5,A6,A7)                           \
    {                                                                          \
        const int cp = c & 1;                                                  \
        unsigned* rw = red_u + ((cp * 2 + sg) * 128 + b) * 10;                 \
        *(uint2*)(rw + 2 * g)     = make_uint2(pk2(A0, A1), pk2(A2, A3));      \
        *(uint2*)(rw + 4 + 2 * g) = make_uint2(pk2(A4, A5), pk2(A6, A7));      \
        if (cp == 1) {                                                         \
            __syncthreads();                                                   \
            const int cp2 = tid >> 8, t2 = tid & 255;                          \
            const int b2 = t2 >> 1, oh = t2 & 1;                               \
            const int cout = c - 1 + cp2;                                      \
            const unsigned* r0p = red_u + ((cp2 * 2 + 0) * 128 + b2) * 10 + oh * 4; \
            const unsigned* r1p = red_u + ((cp2 * 2 + 1) * 128 + b2) * 10 + oh * 4; \
            const uint2 xa = *(const uint2*)r0p;                               \
            const uint2 xb2 = *(const uint2*)(r0p + 2);                        \
            const uint2 ya = *(const uint2*)r1p;                               \
            const uint2 yb = *(const uint2*)(r1p + 2);                         \
            unsigned ua[4] = {xa.x, xa.y, xb2.x, xb2.y};                       \
            unsigned ub[4] = {ya.x, ya.y, yb.x, yb.y};                         \
            unsigned uo[4];                                                    \
            _Pragma("unroll")                                                  \
            for (int j = 0; j < 4; ++j) {                                      \
                const float2 fa = __half22float2(*(const __half2*)&ua[j]);     \
                const float2 fb = __half22float2(*(const __half2*)&ub[j]);     \
                uo[j] = pk2(fa.x + fb.x, fa.y + fb.y);                         \
            }                                                                  \
            *(uint4*)(part + ((size_t)blockIdx.x * C_ + cout) * (B_ * O_)      \
                      + b2 * O_ + oh * 8) = make_uint4(uo[0], uo[1], uo[2], uo[3]); \
            __syncthreads();                                                   \
        }                                                                      \
    }

    if (mode) {
        // ================= mode 1: softmax-weighted =================
        // ---- phase 2: denominators d[r] = sum_c exp2(p[c,r]) ----
        float dinv[4];
        {
            float dacc[4] = {0.f, 0.f, 0.f, 0.f};
            // depth-1 prefetch of (va,vb)
            float4 va = *(const float4*)(vbase);
            float4 vb = *(const float4*)(vbase + 8);
#pragma unroll 1
            for (int c = 0; c < C_; ++c) {
                const int cn = (c + 1 < C_) ? c + 1 : c;     // clamped (no UB)
                const float4 nva = *(const float4*)(vbase + (size_t)cn * (B_ * O_));
                const float4 nvb = *(const float4*)(vbase + (size_t)cn * (B_ * O_) + 8);
#pragma unroll
                for (int rp = 0; rp < 4; ++rp) {
                    const int woff = act ? ((c * 8 + 2 * rp + g) * WROW + o_m * 4)
                                         : (WZERO * WROW);
                    const half8 a = *(const half8*)(wbase + woff);
                    const f32x16 u = __builtin_amdgcn_mfma_f32_32x32x16_f16(a, xbr[rp], zero16, 0, 0, 0);
                    const float p0 = DOT8(u, 0, va, vb);
                    const float p1 = DOT8(u, 8, va, vb);
                    const float send = g ? p0 : p1;
                    const float recv = __shfl_xor(send, 32);
                    const float pg = (g ? p1 : p0) + recv;
                    dacc[rp] += EXP2F(pg);
                }
                va = nva; vb = nvb;
            }
#pragma unroll
            for (int rp = 0; rp < 4; ++rp) dinv[rp] = 1.0f / dacc[rp];
        }

        // ---- phase 3: weighted accumulation via full-A MFMA ----
        {
            float4 va = *(const float4*)(vbase);
            float4 vb = *(const float4*)(vbase + 8);
#pragma unroll 1
            for (int c = 0; c < C_; ++c) {
                const int cn = (c + 1 < C_) ? c + 1 : c;
                const float4 nva = *(const float4*)(vbase + (size_t)cn * (B_ * O_));
                const float4 nvb = *(const float4*)(vbase + (size_t)cn * (B_ * O_) + 8);
                f32x16 sacc;
#pragma unroll
                for (int rp = 0; rp < 4; ++rp) {
                    const int wslot = (c * 8 + 2 * rp + g) * WROW + o_m * 4;
                    const int woff_d = act ? wslot : (WZERO * WROW);
                    const half8 ad = *(const half8*)(wbase + woff_d);
                    const f32x16 u = __builtin_amdgcn_mfma_f32_32x32x16_f16(ad, xbr[rp], zero16, 0, 0, 0);
                    const float p0 = DOT8(u, 0, va, vb);
                    const float p1 = DOT8(u, 8, va, vb);
                    const float send = g ? p0 : p1;
                    const float recv = __shfl_xor(send, 32);
                    const float pg = (g ? p1 : p0) + recv;
                    const float w_own = EXP2F(pg) * dinv[rp];    // cij for r = 2rp+g
                    const _Float16 wh = (_Float16)w_own;
                    half8 xc;
#pragma unroll
                    for (int j = 0; j < 8; ++j) xc[j] = (_Float16)(xbr[rp][j] * wh);
                    const int woff_f = actf ? wslot : (WZERO * WROW);
                    const half8 af = *(const half8*)(wbase + woff_f);
                    sacc = __builtin_amdgcn_mfma_f32_32x32x16_f16(af, xc,
                                                                  rp == 0 ? zero16 : sacc, 0, 0, 0);
                }
                RED_WRITE_AND_FLUSH(sacc[0], sacc[1], sacc[2], sacc[3],
                                    sacc[4], sacc[5], sacc[6], sacc[7]);
                va = nva; vb = nvb;
            }
        }
    } else {
        // ================= mode 0: uniform weights 0.1 (full-A, no r-fold) =====
#pragma unroll 1
        for (int c = 0; c < C_; ++c) {
            f32x16 acc;
#pragma unroll
            for (int rp = 0; rp < 4; ++rp) {
                const int woff_f = actf ? ((c * 8 + 2 * rp + g) * WROW + o_m * 4)
                                        : (WZERO * WROW);
                const half8 af = *(const half8*)(wbase + woff_f);
                acc = __builtin_amdgcn_mfma_f32_32x32x16_f16(af, xbr[rp],
                                                             rp == 0 ? zero16 : acc, 0, 0, 0);
            }
            const float f0 = acc[0] * 0.1f, f1 = acc[1] * 0.1f;
            const float f2 = acc[2] * 0.1f, f3 = acc[3] * 0.1f;
            const float f4 = acc[4] * 0.1f, f5 = acc[5] * 0.1f;
            const float f6 = acc[6] * 0.1f, f7 = acc[7] * 0.1f;
            RED_WRITE_AND_FLUSH(f0, f1, f2, f3, f4, f5, f6, f7);
        }
    }
#undef RED_WRITE_AND_FLUSH
}

// ---------------------------------------------------------------------------
// finish_fused: vectorized uint4 loads (16 B/lane). grid 80, block 512.
// Block owns 32 uint4-cols; thread (jj = tid&31, sgp = tid>>5) sums 32 slots
// of col blockIdx*32+jj. LDS tree red[16][32][9] (pad 9 breaks 8-way bank
// conflict), then lanes 0..255 squash (16-lane groups = 16 o's) and write.
// Modes 0/1 write vsum PRE-SCALED by log2e (fused uses native exp2);
// accumulation vsum += v*log2e is the scaled b_ij (linear, commutes).
// mode 2: out UNSCALED.
// ---------------------------------------------------------------------------
__global__ __launch_bounds__(512) void finish_fused(const __half* __restrict__ part,
                                                    float* __restrict__ vsum,   // [C][B][16] (x log2e)
                                                    float* __restrict__ out,    // [B][C][16]
                                                    int mode) {
    __shared__ float red[16][32][9];
    const int jj  = threadIdx.x & 31;
    const int sgp = threadIdx.x >> 5;          // slot-sixteenth 0..15
    const size_t col = (size_t)blockIdx.x * 32 + jj;   // uint4-column 0..2559

    const uint4* pu = (const uint4*)part + (size_t)(sgp * 32) * (SBO / 8) + col;
    float s[8];
#pragma unroll
    for (int e = 0; e < 8; ++e) s[e] = 0.f;
#pragma unroll 8
    for (int ss = 0; ss < 32; ++ss) {
        const uint4 v = pu[(size_t)ss * (SBO / 8)];
        const float2 f0 = __half22float2(*(const __half2*)&v.x);
        const float2 f1 = __half22float2(*(const __half2*)&v.y);
        const float2 f2 = __half22float2(*(const __half2*)&v.z);
        const float2 f3 = __half22float2(*(const __half2*)&v.w);
        s[0] += f0.x; s[1] += f0.y; s[2] += f1.x; s[3] += f1.y;
        s[4] += f2.x; s[5] += f2.y; s[6] += f3.x; s[7] += f3.y;
    }
#pragma unroll
    for (int e = 0; e < 8; ++e) red[sgp][jj][e] = s[e];
    __syncthreads();

    if (threadIdx.x < 256) {
        const int j2 = threadIdx.x >> 3;       // col within block 0..31
        const int e  = threadIdx.x & 7;
        float sum = red[0][j2][e];
#pragma unroll
        for (int k = 1; k < 16; ++k) sum += red[k][j2][e];

        float sq = sum * sum;
        sq += __shfl_xor(sq, 1);
        sq += __shfl_xor(sq, 2);
        sq += __shfl_xor(sq, 4);
        sq += __shfl_xor(sq, 8);
        const float scale = sq / ((1.0f + sq) * sqrtf(sq + 1e-8f));
        const float v = scale * sum;
        const size_t h = ((size_t)blockIdx.x * 32 + j2) * 8 + e;   // index in [C][B][16]

        if (mode == 0) {
            vsum[h] = v * LOG2E;
        } else if (mode == 1) {
            vsum[h] += v * LOG2E;
        } else {
            const int o = (int)(h & 15), b = (int)((h >> 4) & 127), c = (int)(h >> 11);
            out[((size_t)b * C_ + c) * O_ + o] = v;
        }
    }
}

extern "C" void kernel_launch(void* const* d_in, const int* in_sizes, int n_in,
                              void* d_out, int out_size, void* d_ws, size_t ws_size,
                              hipStream_t stream) {
    const float* x = (const float*)d_in[0];   // [B,R,8]
    const float* w = (const float*)d_in[1];   // [C,R,8,16]
    float* out = (float*)d_out;               // [B,C,16]

    __half* part = (__half*)d_ws;                          // 512*20480 fp16 = 21.0 MB
    float* vsum  = (float*)(part + (size_t)SLOTS * SBO);   // 20480 f ([C][B][16])

    const dim3 fgrid(R_ / 16);             // 512 blocks of 512 threads
    const dim3 ggrid(80);                  // finish_fused (32 uint4-cols each)

    for (int it = 0; it < 3; ++it) {
        const int mode = (it > 0);
        const int fmode = (it == 2) ? 2 : it;   // finish: 0=set, 1=add, 2=out
        fused_iter<<<fgrid, 512, 0, stream>>>(x, w, vsum, part, mode);
        finish_fused<<<ggrid, 512, 0, stream>>>(part, vsum, out, fmode);
    }
}